// Round 8
// baseline (356.908 us; speedup 1.0000x reference)
//
#include <hip/hip_runtime.h>

#define P_ 3136
#define NTOT 50176
#define EPSV 1e-5f

typedef __bf16 bf16x8 __attribute__((ext_vector_type(8)));
typedef float f32x4 __attribute__((ext_vector_type(4)));
typedef unsigned short u16x8 __attribute__((ext_vector_type(8)));
typedef unsigned short u16x4 __attribute__((ext_vector_type(4)));

__device__ __forceinline__ unsigned short f2bf(float f) {
    unsigned u = __builtin_bit_cast(unsigned, f);
    unsigned r = u + 0x7fffu + ((u >> 16) & 1u);
    return (unsigned short)(r >> 16);
}
__device__ __forceinline__ float bf2f(unsigned short h) {
    unsigned u = ((unsigned)h) << 16;
    return __builtin_bit_cast(float, u);
}
// tanh-approx GELU (max abs err ~1e-3; clamp avoids exp overflow NaN)
__device__ __forceinline__ float gelu_fast(float x) {
    float x2 = x * x;
    float u2 = x * (1.5957691216f + 0.0713548162f * x2);
    u2 = fminf(u2, 80.0f);
    float e = __expf(u2);
    return x * e * __builtin_amdgcn_rcpf(e + 1.0f);
}
__device__ __forceinline__ void gload16(const void* g, void* l) {
    __builtin_amdgcn_global_load_lds(
        (const __attribute__((address_space(1))) void*)g,
        (__attribute__((address_space(3))) void*)l, 16, 0, 0);
}
__device__ __forceinline__ bf16x8 ldlds(const char* p) {
    return __builtin_bit_cast(bf16x8, *(const u16x8*)p);
}
__device__ __forceinline__ bf16x8 ldg8(const unsigned short* p) {
    return __builtin_bit_cast(bf16x8, *(const u16x8*)p);
}

// ---------------- prep: weights fp32 -> bf16, + BN scale/shift ----------------
__global__ __launch_bounds__(256)
void prep_wb(const float* __restrict__ w1, const float* __restrict__ w2,
             const float* __restrict__ w3,
             unsigned short* __restrict__ o1, unsigned short* __restrict__ o2,
             unsigned short* __restrict__ o3,
             const float* b1, const float* g1, const float* be1, const float* m1, const float* v1,
             const float* b2, const float* g2, const float* be2, const float* m2, const float* v2,
             const float* b3, const float* g3, const float* be3, const float* m3, const float* v3,
             float* bn1, float* bn2, float* bn3)
{
    int i = blockIdx.x * 256 + threadIdx.x;
    const int n1 = 384 * 384 / 4, n2 = 768 * 768 / 4, n3 = 384 * 768 / 4;
    if (i < n1 + n2 + n3) {
        const float* src; unsigned short* dst; int j;
        if (i < n1)           { src = w1; dst = o1; j = i; }
        else if (i < n1 + n2) { src = w2; dst = o2; j = i - n1; }
        else                  { src = w3; dst = o3; j = i - n1 - n2; }
        float4 f = *(const float4*)(src + (size_t)j * 4);
        u16x4 pk = { f2bf(f.x), f2bf(f.y), f2bf(f.z), f2bf(f.w) };
        *(u16x4*)(dst + (size_t)j * 4) = pk;
    } else {
        int k = i - (n1 + n2 + n3);  // 0..1535
        const float *pb, *pg, *pbe, *pm, *pv; float* dst; int o, M;
        if (k < 384)       { pb=b1; pg=g1; pbe=be1; pm=m1; pv=v1; dst=bn1; o=k;        M=384; }
        else if (k < 1152) { pb=b2; pg=g2; pbe=be2; pm=m2; pv=v2; dst=bn2; o=k-384;    M=768; }
        else               { pb=b3; pg=g3; pbe=be3; pm=m3; pv=v3; dst=bn3; o=k-1152;   M=384; }
        float inv = pg[o] / sqrtf(pv[o] + EPSV);
        dst[o]     = inv;
        dst[M + o] = (pb[o] - pm[o]) * inv + pbe[o];
    }
}

// ---------------- prep: x [b][c][p] fp32 -> xT [bp][c] bf16 ----------------
__global__ __launch_bounds__(256)
void prep_xT(const float* __restrict__ x, unsigned short* __restrict__ xT)
{
    __shared__ float tl[64][65];
    const int t = threadIdx.x;
    const int c0 = blockIdx.x * 64;
    const int p0 = blockIdx.y * 64;
    const int b  = blockIdx.z;
    const float* xb = x + ((size_t)b * 384 + c0) * P_ + p0;
    {
        int c = t >> 2, j0 = (t & 3) * 16;
        #pragma unroll
        for (int j = 0; j < 16; j += 4) {
            float4 f4 = *(const float4*)(xb + (size_t)c * P_ + j0 + j);
            tl[c][j0 + j]     = f4.x; tl[c][j0 + j + 1] = f4.y;
            tl[c][j0 + j + 2] = f4.z; tl[c][j0 + j + 3] = f4.w;
        }
    }
    __syncthreads();
    {
        int p = t >> 2, c1 = (t & 3) * 16;
        unsigned short buf[16];
        #pragma unroll
        for (int j = 0; j < 16; ++j) buf[j] = f2bf(tl[c1 + j][p]);
        unsigned short* dst = xT + ((size_t)b * P_ + p0 + p) * 384 + c0 + c1;
        *(u16x8*)dst       = *(u16x8*)buf;
        *(u16x8*)(dst + 8) = *(u16x8*)(buf + 8);
    }
}

// ============ direct-A GEMM: 128x128x64, 256 thr (4 waves 2x2, wave 64x64) ============
// A = W [MDIM][KD] bf16 (small, L2-resident): loaded DIRECT global->VGPR per-lane,
//     register double-buffered (afrE/afrO), prefetched one K-tile ahead.
// B = In [NTOT][KD] bf16: LDS double-buffer 2x16KB via global_load_lds.
// Per K-tile: 8 A-loads + 4 B-DMA issued for kt+1, then vmcnt(12) -> kt complete.
// LDS reads halved vs all-LDS design (8 ds_read_b128/wave/tile).
// EPI 0: BN -> bf16 [col][768]+o0.  EPI 1: +gelu.  EPI 2: BN+res -> fp32 [b][o][p].
template<int KD, int MDIM, int EPI>
__global__ __launch_bounds__(256, 2)
void gemmD(const unsigned short* __restrict__ W,
           const unsigned short* __restrict__ In,
           void* __restrict__ OutV,
           const float* __restrict__ bnp,
           const float* __restrict__ res)
{
    constexpr int NT = KD / 64;
    constexpr int MT = MDIM / 128;
    __shared__ __align__(16) char lds[36864];  // B dbuf 32KB; epilogue overlay <=35KB

    const int t    = threadIdx.x;
    const int lane = t & 63;
    const int wave = t >> 6;
    const int wm = wave >> 1, wn = wave & 1;
    const int fr = lane & 15, fg = lane >> 4;

    // bijective XCD chunk swizzle, M-fastest (MT consecutive wg share a B panel)
    const int nwg = gridDim.x;
    int id = blockIdx.x;
    int q = nwg >> 3, r = nwg & 7;
    int xcd = id & 7, pos = id >> 3;
    int wg = (xcd < r ? xcd * (q + 1) : r * (q + 1) + (xcd - r) * q) + pos;
    const int m0 = (wg % MT) * 128;
    const int n0 = (wg / MT) * 128;

    // ---- B staging: 16KB/K-tile = 4 gloads of 4KB ----
    const int pcu  = (((t & 7) ^ ((t >> 3) & 7)) << 3); // swizzled source col (ushorts)
    const int srow = t >> 3;                             // 0..31
    const unsigned short* pB[4];
    #pragma unroll
    for (int i = 0; i < 4; ++i)
        pB[i] = In + (size_t)(n0 + i * 32 + srow) * KD + pcu;
    auto dmaB = [&](int kt) {
        int kk = (kt < NT ? kt : NT - 1) * 64;
        char* base = lds + (kt & 1) * 16384 + t * 16;
        #pragma unroll
        for (int i = 0; i < 4; ++i) gload16(pB[i] + kk, base + i * 4096);
    };

    // ---- A direct per-lane fragment pointers ----
    const unsigned short* pA[4];
    #pragma unroll
    for (int mf = 0; mf < 4; ++mf)
        pA[mf] = W + (size_t)(m0 + wm * 64 + mf * 16 + fr) * KD + fg * 8;

    const int ko0 = (fg * 16) ^ ((fr & 7) << 4);
    const int ko1 = (64 + fg * 16) ^ ((fr & 7) << 4);
    const int brow = wn * 64 + fr;

    bf16x8 afrE[4][2], afrO[4][2];
    f32x4 acc[4][4] = {};

    auto body = [&](int kt, int par, bf16x8 (&cur)[4][2], bf16x8 (&nxt)[4][2]) {
        const int kta = (kt + 1 < NT ? kt + 1 : NT - 1) * 64;
        #pragma unroll
        for (int mf = 0; mf < 4; ++mf) {
            nxt[mf][0] = ldg8(pA[mf] + kta);
            nxt[mf][1] = ldg8(pA[mf] + kta + 32);
        }
        dmaB(kt + 1);
        asm volatile("s_waitcnt vmcnt(12)" ::: "memory"); // kt's A + B-DMA done
        __builtin_amdgcn_s_barrier();
        __builtin_amdgcn_sched_barrier(0);

        const char* base = lds + par * 16384;
        bf16x8 bfr[4][2];
        #pragma unroll
        for (int nf = 0; nf < 4; ++nf) {
            bfr[nf][0] = ldlds(base + (brow + nf * 16) * 128 + ko0);
            bfr[nf][1] = ldlds(base + (brow + nf * 16) * 128 + ko1);
        }
        #pragma unroll
        for (int ks = 0; ks < 2; ++ks)
            #pragma unroll
            for (int mf = 0; mf < 4; ++mf)
                #pragma unroll
                for (int nf = 0; nf < 4; ++nf)
                    acc[mf][nf] = __builtin_amdgcn_mfma_f32_16x16x32_bf16(
                        cur[mf][ks], bfr[nf][ks], acc[mf][nf], 0, 0, 0);
        asm volatile("s_waitcnt lgkmcnt(0)" ::: "memory");
        __builtin_amdgcn_sched_barrier(0);
        __builtin_amdgcn_s_barrier(); // buf par free for DMA overwrite
    };

    // prologue: tile 0 -> afrE + DMA(0)   [12 outstanding]
    #pragma unroll
    for (int mf = 0; mf < 4; ++mf) {
        afrE[mf][0] = ldg8(pA[mf]);
        afrE[mf][1] = ldg8(pA[mf] + 32);
    }
    dmaB(0);

    for (int kt = 0; kt < NT; kt += 2) {
        body(kt,     0, afrE, afrO);
        body(kt + 1, 1, afrO, afrE);
    }

    // drain DMA + sync before overlaying LDS for the epilogue
    asm volatile("s_waitcnt vmcnt(0)" ::: "memory");
    __builtin_amdgcn_s_barrier();

    if (EPI < 2) {
        // [128 col][136 o-slot] u16 staging (row stride 272B -> 16B aligned)
        unsigned short* eL = (unsigned short*)lds;
        unsigned short* Out = (unsigned short*)OutV;
        #pragma unroll
        for (int mf = 0; mf < 4; ++mf) {
            const int o_l = wm * 64 + mf * 16 + fg * 4;
            f32x4 inv = *(const f32x4*)(bnp + m0 + o_l);
            f32x4 sh  = *(const f32x4*)(bnp + MDIM + m0 + o_l);
            #pragma unroll
            for (int nf = 0; nf < 4; ++nf) {
                const int col_l = wn * 64 + nf * 16 + fr;
                u16x4 pk;
                #pragma unroll
                for (int rr = 0; rr < 4; ++rr) {
                    float v = acc[mf][nf][rr] * inv[rr] + sh[rr];
                    if (EPI == 1) v = gelu_fast(v);
                    pk[rr] = f2bf(v);
                }
                *(u16x4*)(eL + col_l * 136 + o_l) = pk;
            }
        }
        __builtin_amdgcn_s_barrier();
        #pragma unroll
        for (int i = 0; i < 8; ++i) {
            const int col_l = (t >> 4) + i * 16;
            const int o8 = (t & 15) * 8;
            u16x8 v = *(const u16x8*)(eL + col_l * 136 + o8);
            *(u16x8*)(Out + (size_t)(n0 + col_l) * 768 + m0 + o8) = v;
        }
    } else {
        // two halves of [64 o][132 col] fp32 staging; coalesced dword IO
        float* eL = (float*)lds;
        float* Out = (float*)OutV;
        #pragma unroll
        for (int h = 0; h < 2; ++h) {
            if (wm == h) {
                #pragma unroll
                for (int mf = 0; mf < 4; ++mf) {
                    const int o_l = mf * 16 + fg * 4;
                    f32x4 inv = *(const f32x4*)(bnp + m0 + h * 64 + o_l);
                    f32x4 sh  = *(const f32x4*)(bnp + MDIM + m0 + h * 64 + o_l);
                    #pragma unroll
                    for (int nf = 0; nf < 4; ++nf) {
                        const int col_l = wn * 64 + nf * 16 + fr;
                        #pragma unroll
                        for (int rr = 0; rr < 4; ++rr)
                            eL[(o_l + rr) * 132 + col_l] =
                                acc[mf][nf][rr] * inv[rr] + sh[rr];
                    }
                }
            }
            __builtin_amdgcn_s_barrier();
            #pragma unroll
            for (int i = 0; i < 32; ++i) {
                const int idx = i * 256 + t;
                const int o_i = idx >> 7, col = idx & 127;
                const int col_g = n0 + col;
                const int b = col_g / P_;
                const int p = col_g - b * P_;
                const size_t adr = (size_t)b * 384 * P_ + (size_t)(m0 + h * 64 + o_i) * P_ + p;
                Out[adr] = eL[o_i * 132 + col] + res[adr];
            }
            __builtin_amdgcn_s_barrier();
        }
    }
}

// ============ fused mrconv: one block per (b, 8-channel group) ============
// Plane (3136 px x 8 ch) in LDS; col/row parity min1/min2 in-LDS; combine; write.
// y-half read once (77MB) + written once. Grid (16 b, 48 cg): b-fastest so the
// 4 c-groups sharing a 64B line map to the same XCD's L2.
__global__ __launch_bounds__(256)
void mr_fused(unsigned short* __restrict__ y)
{
    __shared__ __align__(16) unsigned short pl[3136 * 8];   // [p][c] 49KB
    __shared__ float mins[4][2][56][8];                      // cm1,cm2,rm1,rm2 14KB
    const int t  = threadIdx.x;
    const int b  = blockIdx.x;
    const int c0 = blockIdx.y * 8;
    unsigned short* yb = y + (size_t)b * P_ * 768;

    for (int i = t; i < P_; i += 256)
        *(u16x8*)(pl + i * 8) = *(const u16x8*)(yb + (size_t)i * 768 + c0);
    __syncthreads();

    #pragma unroll
    for (int j = 0; j < 7; ++j) {               // 1792 tasks = 7 x 256
        const int id = j * 256 + t;
        const int c  = id & 7;
        const int qn = id >> 3;                  // 0..223
        const int isRow = qn >= 112;
        const int qq  = isRow ? qn - 112 : qn;
        const int par = qq >= 56 ? 1 : 0;
        const int idx = qq - par * 56;
        int p  = isRow ? idx * 56 + par : par * 56 + idx;
        const int st = isRow ? 2 : 112;
        float m1 = 3.4e38f, m2 = 3.4e38f;
        for (int k = 0; k < 28; ++k, p += st) {
            float v = bf2f(pl[p * 8 + c]);
            if (v < m1) { m2 = m1; m1 = v; } else if (v < m2) m2 = v;
        }
        const int ws = isRow ? 2 : 0;
        mins[ws][par][idx][c]     = m1;
        mins[ws + 1][par][idx][c] = m2;
    }
    __syncthreads();

    for (int i = t; i < P_; i += 256) {
        const int h = i / 56, w = i - h * 56;
        u16x8 vv = *(const u16x8*)(pl + i * 8);
        u16x8 out;
        #pragma unroll
        for (int c = 0; c < 8; ++c) {
            float v  = bf2f(vv[c]);
            float c1 = mins[0][h & 1][w][c];
            float c2 = mins[1][h & 1][w][c];
            float mh = v > c1 ? c1 : c2;
            float r1 = mins[2][w & 1][h][c];
            float r2 = mins[3][w & 1][h][c];
            float mw = v > r1 ? r1 : r2;
            out[c] = f2bf(fmaxf(0.0f, v - fminf(mh, mw)));
        }
        *(u16x8*)(yb + (size_t)i * 768 + 384 + c0) = out;
    }
}

extern "C" void kernel_launch(void* const* d_in, const int* in_sizes, int n_in,
                              void* d_out, int out_size, void* d_ws, size_t ws_size,
                              hipStream_t stream)
{
    const float* x      = (const float*)d_in[0];
    const float* fc1_w  = (const float*)d_in[1];
    const float* fc1_b  = (const float*)d_in[2];
    const float* fc1_g  = (const float*)d_in[3];
    const float* fc1_be = (const float*)d_in[4];
    const float* fc1_m  = (const float*)d_in[5];
    const float* fc1_v  = (const float*)d_in[6];
    const float* gc_w   = (const float*)d_in[7];
    const float* gc_b   = (const float*)d_in[8];
    const float* gc_g   = (const float*)d_in[9];
    const float* gc_be  = (const float*)d_in[10];
    const float* gc_m   = (const float*)d_in[11];
    const float* gc_v   = (const float*)d_in[12];
    const float* fc2_w  = (const float*)d_in[13];
    const float* fc2_b  = (const float*)d_in[14];
    const float* fc2_g  = (const float*)d_in[15];
    const float* fc2_be = (const float*)d_in[16];
    const float* fc2_m  = (const float*)d_in[17];
    const float* fc2_v  = (const float*)d_in[18];

    char* ws = (char*)d_ws;
    unsigned short* y   = (unsigned short*)ws;                       // [NTOT][768] bf16
    unsigned short* g   = y + (size_t)NTOT * 768;                    // [NTOT][768] bf16
    unsigned short* xT  = g + (size_t)NTOT * 768;                    // [NTOT][384] bf16
    unsigned short* wb1 = xT + (size_t)NTOT * 384;                   // [384][384]
    unsigned short* wb2 = wb1 + 384 * 384;                           // [768][768]
    unsigned short* wb3 = wb2 + 768 * 768;                           // [384][768]
    float* bn1 = (float*)(wb3 + 384 * 768);                          // [2][384]
    float* bn2 = bn1 + 2 * 384;                                      // [2][768]
    float* bn3 = bn2 + 2 * 768;                                      // [2][384]

    // weights->bf16 (1008 blocks) + BN fold (6 blocks)
    prep_wb<<<1014, 256, 0, stream>>>(fc1_w, gc_w, fc2_w, wb1, wb2, wb3,
                                      fc1_b, fc1_g, fc1_be, fc1_m, fc1_v,
                                      gc_b, gc_g, gc_be, gc_m, gc_v,
                                      fc2_b, fc2_g, fc2_be, fc2_m, fc2_v,
                                      bn1, bn2, bn3);
    prep_xT<<<dim3(6, 49, 16), 256, 0, stream>>>(x, xT);

    // y[:, 0:384] = bn(fc1 @ x)
    gemmD<384, 384, 0><<<dim3(3 * 392), 256, 0, stream>>>(wb1, xT, y, bn1, nullptr);
    // y[:, 384:768] = mrconv (single fused pass)
    mr_fused<<<dim3(16, 48), 256, 0, stream>>>(y);
    // g = gelu(bn(gc @ y))
    gemmD<768, 768, 1><<<dim3(6 * 392), 256, 0, stream>>>(wb2, y, g, bn2, nullptr);
    // out = bn(fc2 @ g) + x
    gemmD<768, 384, 2><<<dim3(3 * 392), 256, 0, stream>>>(wb3, g, (void*)d_out, bn3, x);
}

// Round 9
// 273.654 us; speedup vs baseline: 1.3042x; 1.3042x over previous
//
#include <hip/hip_runtime.h>

#define P_ 3136
#define NTOT 50176
#define EPSV 1e-5f

typedef __bf16 bf16x8 __attribute__((ext_vector_type(8)));
typedef float f32x4 __attribute__((ext_vector_type(4)));
typedef unsigned short u16x8 __attribute__((ext_vector_type(8)));
typedef unsigned short u16x4 __attribute__((ext_vector_type(4)));

__device__ __forceinline__ unsigned short f2bf(float f) {
    unsigned u = __builtin_bit_cast(unsigned, f);
    unsigned r = u + 0x7fffu + ((u >> 16) & 1u);
    return (unsigned short)(r >> 16);
}
__device__ __forceinline__ float bf2f(unsigned short h) {
    unsigned u = ((unsigned)h) << 16;
    return __builtin_bit_cast(float, u);
}
// tanh-approx GELU (max abs err ~1e-3; clamp avoids exp overflow NaN)
__device__ __forceinline__ float gelu_fast(float x) {
    float x2 = x * x;
    float u2 = x * (1.5957691216f + 0.0713548162f * x2);
    u2 = fminf(u2, 80.0f);
    float e = __expf(u2);
    return x * e * __builtin_amdgcn_rcpf(e + 1.0f);
}
__device__ __forceinline__ void gload16(const void* g, void* l) {
    __builtin_amdgcn_global_load_lds(
        (const __attribute__((address_space(1))) void*)g,
        (__attribute__((address_space(3))) void*)l, 16, 0, 0);
}
__device__ __forceinline__ bf16x8 ldlds(const char* p) {
    return __builtin_bit_cast(bf16x8, *(const u16x8*)p);
}

// ---------------- prep: weights fp32 -> bf16, + BN scale/shift ----------------
__global__ __launch_bounds__(256)
void prep_wb(const float* __restrict__ w1, const float* __restrict__ w2,
             const float* __restrict__ w3,
             unsigned short* __restrict__ o1, unsigned short* __restrict__ o2,
             unsigned short* __restrict__ o3,
             const float* b1, const float* g1, const float* be1, const float* m1, const float* v1,
             const float* b2, const float* g2, const float* be2, const float* m2, const float* v2,
             const float* b3, const float* g3, const float* be3, const float* m3, const float* v3,
             float* bn1, float* bn2, float* bn3)
{
    int i = blockIdx.x * 256 + threadIdx.x;
    const int n1 = 384 * 384 / 4, n2 = 768 * 768 / 4, n3 = 384 * 768 / 4;
    if (i < n1 + n2 + n3) {
        const float* src; unsigned short* dst; int j;
        if (i < n1)           { src = w1; dst = o1; j = i; }
        else if (i < n1 + n2) { src = w2; dst = o2; j = i - n1; }
        else                  { src = w3; dst = o3; j = i - n1 - n2; }
        float4 f = *(const float4*)(src + (size_t)j * 4);
        u16x4 pk = { f2bf(f.x), f2bf(f.y), f2bf(f.z), f2bf(f.w) };
        *(u16x4*)(dst + (size_t)j * 4) = pk;
    } else {
        int k = i - (n1 + n2 + n3);  // 0..1535
        const float *pb, *pg, *pbe, *pm, *pv; float* dst; int o, M;
        if (k < 384)       { pb=b1; pg=g1; pbe=be1; pm=m1; pv=v1; dst=bn1; o=k;        M=384; }
        else if (k < 1152) { pb=b2; pg=g2; pbe=be2; pm=m2; pv=v2; dst=bn2; o=k-384;    M=768; }
        else               { pb=b3; pg=g3; pbe=be3; pm=m3; pv=v3; dst=bn3; o=k-1152;   M=384; }
        float inv = pg[o] / sqrtf(pv[o] + EPSV);
        dst[o]     = inv;
        dst[M + o] = (pb[o] - pm[o]) * inv + pbe[o];
    }
}

// ---------------- prep: x [b][c][p] fp32 -> xT [bp][c] bf16 ----------------
__global__ __launch_bounds__(256)
void prep_xT(const float* __restrict__ x, unsigned short* __restrict__ xT)
{
    __shared__ float tl[64][65];
    const int t = threadIdx.x;
    const int c0 = blockIdx.x * 64;
    const int p0 = blockIdx.y * 64;
    const int b  = blockIdx.z;
    const float* xb = x + ((size_t)b * 384 + c0) * P_ + p0;
    {
        int c = t >> 2, j0 = (t & 3) * 16;
        #pragma unroll
        for (int j = 0; j < 16; j += 4) {
            float4 f4 = *(const float4*)(xb + (size_t)c * P_ + j0 + j);
            tl[c][j0 + j]     = f4.x; tl[c][j0 + j + 1] = f4.y;
            tl[c][j0 + j + 2] = f4.z; tl[c][j0 + j + 3] = f4.w;
        }
    }
    __syncthreads();
    {
        int p = t >> 2, c1 = (t & 3) * 16;
        unsigned short buf[16];
        #pragma unroll
        for (int j = 0; j < 16; ++j) buf[j] = f2bf(tl[c1 + j][p]);
        unsigned short* dst = xT + ((size_t)b * P_ + p0 + p) * 384 + c0 + c1;
        *(u16x8*)dst       = *(u16x8*)buf;
        *(u16x8*)(dst + 8) = *(u16x8*)(buf + 8);
    }
}

// ============ fine GEMM: 128x128 tile, BK=32, 256 thr (4 waves 2x2, wave 64x64) ============
// A = W [MDIM][KD], B = In [NTOT][KD], both bf16 k-contig rows.
// LDS 2x16KB double-buffer {A 8KB, B 8KB} -> 34KB block -> 4 blocks/CU (16 waves).
// Rows are 64B; 16B-granule swizzle key (row&3), inverse pre-applied to global source.
// Counted loop: stage(kt+1) first (4 gloads), vmcnt(4) -> tile kt ready; never drains.
// EPI 0: BN -> bf16 [col][768]+o0.  EPI 1: +gelu.  EPI 2: BN+res -> fp32 [b][o][p].
template<int KD, int MDIM, int EPI>
__global__ __launch_bounds__(256, 4)
void gemmF(const unsigned short* __restrict__ W,
           const unsigned short* __restrict__ In,
           void* __restrict__ OutV,
           const float* __restrict__ bnp,
           const float* __restrict__ res)
{
    constexpr int NT = KD / 32;
    constexpr int MT = MDIM / 128;
    __shared__ __align__(16) char lds[34816];  // 32KB staging; epilogue overlay <=34.8KB

    const int t    = threadIdx.x;
    const int lane = t & 63;
    const int wave = t >> 6;
    const int wm = wave >> 1, wn = wave & 1;
    const int fr = lane & 15, fg = lane >> 4;

    // bijective XCD chunk swizzle, M-fastest (MT consecutive wg share a B panel)
    const int nwg = gridDim.x;
    int id = blockIdx.x;
    int q = nwg >> 3, r = nwg & 7;
    int xcd = id & 7, pos = id >> 3;
    int wg = (xcd < r ? xcd * (q + 1) : r * (q + 1) + (xcd - r) * q) + pos;
    const int m0 = (wg % MT) * 128;
    const int n0 = (wg / MT) * 128;

    // ---- staging: 16KB/K-tile = 4 gloads (A rows 0-63, A 64-127, B 0-63, B 64-127) ----
    const int pcu  = (((t & 3) ^ ((t >> 2) & 3)) << 3); // swizzled source granule (ushorts)
    const int srow = t >> 2;                             // 0..63
    const unsigned short* pA[2];
    const unsigned short* pB[2];
    #pragma unroll
    for (int i = 0; i < 2; ++i) {
        pA[i] = W  + (size_t)(m0 + i * 64 + srow) * KD + pcu;
        pB[i] = In + (size_t)(n0 + i * 64 + srow) * KD + pcu;
    }
    auto stage = [&](int kt) {
        int kk = (kt < NT ? kt : NT - 1) * 32;
        char* base = lds + (kt & 1) * 16384 + t * 16;
        gload16(pA[0] + kk, base);
        gload16(pA[1] + kk, base + 4096);
        gload16(pB[0] + kk, base + 8192);
        gload16(pB[1] + kk, base + 12288);
    };

    const int ko = (fg * 16) ^ ((fr & 3) << 4);  // byte offset within 64B row
    const int arow = wm * 64 + fr;
    const int brow = wn * 64 + fr;

    f32x4 acc[4][4] = {};

    stage(0);

    for (int kt = 0; kt < NT; ++kt) {
        stage(kt + 1);
        asm volatile("s_waitcnt vmcnt(4)" ::: "memory"); // tile kt fully in LDS
        __builtin_amdgcn_s_barrier();
        __builtin_amdgcn_sched_barrier(0);               // reads stay below barrier

        const char* base = lds + (kt & 1) * 16384;
        bf16x8 afr[4], bfr[4];
        #pragma unroll
        for (int mf = 0; mf < 4; ++mf)
            afr[mf] = ldlds(base + (arow + mf * 16) * 64 + ko);
        #pragma unroll
        for (int nf = 0; nf < 4; ++nf)
            bfr[nf] = ldlds(base + 8192 + (brow + nf * 16) * 64 + ko);
        // compiler inserts counted lgkmcnt before each dependent MFMA -> overlap
        #pragma unroll
        for (int mf = 0; mf < 4; ++mf)
            #pragma unroll
            for (int nf = 0; nf < 4; ++nf)
                acc[mf][nf] = __builtin_amdgcn_mfma_f32_16x16x32_bf16(
                    afr[mf], bfr[nf], acc[mf][nf], 0, 0, 0);
        asm volatile("s_waitcnt lgkmcnt(0)" ::: "memory"); // ~free: MFMAs consumed all
        __builtin_amdgcn_sched_barrier(0);
        __builtin_amdgcn_s_barrier(); // all waves done reading buf kt
    }

    // drain DMA + sync before overlaying LDS for the epilogue
    asm volatile("s_waitcnt vmcnt(0)" ::: "memory");
    __builtin_amdgcn_s_barrier();

    if (EPI < 2) {
        // [128 col][136 o-slot] u16 staging (row stride 272B -> 16B aligned)
        unsigned short* eL = (unsigned short*)lds;
        unsigned short* Out = (unsigned short*)OutV;
        #pragma unroll
        for (int mf = 0; mf < 4; ++mf) {
            const int o_l = wm * 64 + mf * 16 + fg * 4;
            f32x4 inv = *(const f32x4*)(bnp + m0 + o_l);
            f32x4 sh  = *(const f32x4*)(bnp + MDIM + m0 + o_l);
            #pragma unroll
            for (int nf = 0; nf < 4; ++nf) {
                const int col_l = wn * 64 + nf * 16 + fr;
                u16x4 pk;
                #pragma unroll
                for (int rr = 0; rr < 4; ++rr) {
                    float v = acc[mf][nf][rr] * inv[rr] + sh[rr];
                    if (EPI == 1) v = gelu_fast(v);
                    pk[rr] = f2bf(v);
                }
                *(u16x4*)(eL + col_l * 136 + o_l) = pk;
            }
        }
        __builtin_amdgcn_s_barrier();
        #pragma unroll
        for (int i = 0; i < 8; ++i) {
            const int col_l = (t >> 4) + i * 16;
            const int o8 = (t & 15) * 8;
            u16x8 v = *(const u16x8*)(eL + col_l * 136 + o8);
            *(u16x8*)(Out + (size_t)(n0 + col_l) * 768 + m0 + o8) = v;
        }
    } else {
        // two halves of [64 o][132 col] fp32 staging; coalesced dword IO
        float* eL = (float*)lds;
        float* Out = (float*)OutV;
        #pragma unroll
        for (int h = 0; h < 2; ++h) {
            if (wm == h) {
                #pragma unroll
                for (int mf = 0; mf < 4; ++mf) {
                    const int o_l = mf * 16 + fg * 4;
                    f32x4 inv = *(const f32x4*)(bnp + m0 + h * 64 + o_l);
                    f32x4 sh  = *(const f32x4*)(bnp + MDIM + m0 + h * 64 + o_l);
                    #pragma unroll
                    for (int nf = 0; nf < 4; ++nf) {
                        const int col_l = wn * 64 + nf * 16 + fr;
                        #pragma unroll
                        for (int rr = 0; rr < 4; ++rr)
                            eL[(o_l + rr) * 132 + col_l] =
                                acc[mf][nf][rr] * inv[rr] + sh[rr];
                    }
                }
            }
            __builtin_amdgcn_s_barrier();
            #pragma unroll
            for (int i = 0; i < 32; ++i) {
                const int idx = i * 256 + t;
                const int o_i = idx >> 7, col = idx & 127;
                const int col_g = n0 + col;
                const int b = col_g / P_;
                const int p = col_g - b * P_;
                const size_t adr = (size_t)b * 384 * P_ + (size_t)(m0 + h * 64 + o_i) * P_ + p;
                Out[adr] = eL[o_i * 132 + col] + res[adr];
            }
            __builtin_amdgcn_s_barrier();
        }
    }
}

// ============ fused mrconv: one block per (b, 8-channel group) ============
// Plane (3136 px x 8 ch) in LDS; col/row parity min1/min2 in-LDS; combine; write.
// y-half read once + written once. Grid (16 b, 48 cg): b-fastest so the
// 4 c-groups sharing a 64B line map to the same XCD's L2.
__global__ __launch_bounds__(256)
void mr_fused(unsigned short* __restrict__ y)
{
    __shared__ __align__(16) unsigned short pl[3136 * 8];   // [p][c] 49KB
    __shared__ float mins[4][2][56][8];                      // cm1,cm2,rm1,rm2 14KB
    const int t  = threadIdx.x;
    const int b  = blockIdx.x;
    const int c0 = blockIdx.y * 8;
    unsigned short* yb = y + (size_t)b * P_ * 768;

    for (int i = t; i < P_; i += 256)
        *(u16x8*)(pl + i * 8) = *(const u16x8*)(yb + (size_t)i * 768 + c0);
    __syncthreads();

    #pragma unroll
    for (int j = 0; j < 7; ++j) {               // 1792 tasks = 7 x 256
        const int id = j * 256 + t;
        const int c  = id & 7;
        const int qn = id >> 3;                  // 0..223
        const int isRow = qn >= 112;
        const int qq  = isRow ? qn - 112 : qn;
        const int par = qq >= 56 ? 1 : 0;
        const int idx = qq - par * 56;
        int p  = isRow ? idx * 56 + par : par * 56 + idx;
        const int st = isRow ? 2 : 112;
        float m1 = 3.4e38f, m2 = 3.4e38f;
        for (int k = 0; k < 28; ++k, p += st) {
            float v = bf2f(pl[p * 8 + c]);
            if (v < m1) { m2 = m1; m1 = v; } else if (v < m2) m2 = v;
        }
        const int ws = isRow ? 2 : 0;
        mins[ws][par][idx][c]     = m1;
        mins[ws + 1][par][idx][c] = m2;
    }
    __syncthreads();

    for (int i = t; i < P_; i += 256) {
        const int h = i / 56, w = i - h * 56;
        u16x8 vv = *(const u16x8*)(pl + i * 8);
        u16x8 out;
        #pragma unroll
        for (int c = 0; c < 8; ++c) {
            float v  = bf2f(vv[c]);
            float c1 = mins[0][h & 1][w][c];
            float c2 = mins[1][h & 1][w][c];
            float mh = v > c1 ? c1 : c2;
            float r1 = mins[2][w & 1][h][c];
            float r2 = mins[3][w & 1][h][c];
            float mw = v > r1 ? r1 : r2;
            out[c] = f2bf(fmaxf(0.0f, v - fminf(mh, mw)));
        }
        *(u16x8*)(yb + (size_t)i * 768 + 384 + c0) = out;
    }
}

extern "C" void kernel_launch(void* const* d_in, const int* in_sizes, int n_in,
                              void* d_out, int out_size, void* d_ws, size_t ws_size,
                              hipStream_t stream)
{
    const float* x      = (const float*)d_in[0];
    const float* fc1_w  = (const float*)d_in[1];
    const float* fc1_b  = (const float*)d_in[2];
    const float* fc1_g  = (const float*)d_in[3];
    const float* fc1_be = (const float*)d_in[4];
    const float* fc1_m  = (const float*)d_in[5];
    const float* fc1_v  = (const float*)d_in[6];
    const float* gc_w   = (const float*)d_in[7];
    const float* gc_b   = (const float*)d_in[8];
    const float* gc_g   = (const float*)d_in[9];
    const float* gc_be  = (const float*)d_in[10];
    const float* gc_m   = (const float*)d_in[11];
    const float* gc_v   = (const float*)d_in[12];
    const float* fc2_w  = (const float*)d_in[13];
    const float* fc2_b  = (const float*)d_in[14];
    const float* fc2_g  = (const float*)d_in[15];
    const float* fc2_be = (const float*)d_in[16];
    const float* fc2_m  = (const float*)d_in[17];
    const float* fc2_v  = (const float*)d_in[18];

    char* ws = (char*)d_ws;
    unsigned short* y   = (unsigned short*)ws;                       // [NTOT][768] bf16
    unsigned short* g   = y + (size_t)NTOT * 768;                    // [NTOT][768] bf16
    unsigned short* xT  = g + (size_t)NTOT * 768;                    // [NTOT][384] bf16
    unsigned short* wb1 = xT + (size_t)NTOT * 384;                   // [384][384]
    unsigned short* wb2 = wb1 + 384 * 384;                           // [768][768]
    unsigned short* wb3 = wb2 + 768 * 768;                           // [384][768]
    float* bn1 = (float*)(wb3 + 384 * 768);                          // [2][384]
    float* bn2 = bn1 + 2 * 384;                                      // [2][768]
    float* bn3 = bn2 + 2 * 768;                                      // [2][384]

    // weights->bf16 (1008 blocks) + BN fold (6 blocks)
    prep_wb<<<1014, 256, 0, stream>>>(fc1_w, gc_w, fc2_w, wb1, wb2, wb3,
                                      fc1_b, fc1_g, fc1_be, fc1_m, fc1_v,
                                      gc_b, gc_g, gc_be, gc_m, gc_v,
                                      fc2_b, fc2_g, fc2_be, fc2_m, fc2_v,
                                      bn1, bn2, bn3);
    prep_xT<<<dim3(6, 49, 16), 256, 0, stream>>>(x, xT);

    // y[:, 0:384] = bn(fc1 @ x)
    gemmF<384, 384, 0><<<dim3(3 * 392), 256, 0, stream>>>(wb1, xT, y, bn1, nullptr);
    // y[:, 384:768] = mrconv (single fused pass)
    mr_fused<<<dim3(16, 48), 256, 0, stream>>>(y);
    // g = gelu(bn(gc @ y))
    gemmF<768, 768, 1><<<dim3(6 * 392), 256, 0, stream>>>(wb2, y, g, bn2, nullptr);
    // out = bn(fc2 @ g) + x
    gemmF<768, 384, 2><<<dim3(3 * 392), 256, 0, stream>>>(wb3, g, (void*)d_out, bn3, x);
}

// Round 10
// 245.770 us; speedup vs baseline: 1.4522x; 1.1135x over previous
//
#include <hip/hip_runtime.h>

#define P_ 3136
#define NTOT 50176
#define EPSV 1e-5f

typedef __bf16 bf16x8 __attribute__((ext_vector_type(8)));
typedef float f32x4 __attribute__((ext_vector_type(4)));
typedef unsigned short u16x8 __attribute__((ext_vector_type(8)));
typedef unsigned short u16x4 __attribute__((ext_vector_type(4)));

__device__ __forceinline__ unsigned short f2bf(float f) {
    unsigned u = __builtin_bit_cast(unsigned, f);
    unsigned r = u + 0x7fffu + ((u >> 16) & 1u);
    return (unsigned short)(r >> 16);
}
__device__ __forceinline__ float bf2f(unsigned short h) {
    unsigned u = ((unsigned)h) << 16;
    return __builtin_bit_cast(float, u);
}
// tanh-approx GELU (max abs err ~1e-3; clamp avoids exp overflow NaN)
__device__ __forceinline__ float gelu_fast(float x) {
    float x2 = x * x;
    float u2 = x * (1.5957691216f + 0.0713548162f * x2);
    u2 = fminf(u2, 80.0f);
    float e = __expf(u2);
    return x * e * __builtin_amdgcn_rcpf(e + 1.0f);
}
__device__ __forceinline__ void gload16(const void* g, void* l) {
    __builtin_amdgcn_global_load_lds(
        (const __attribute__((address_space(1))) void*)g,
        (__attribute__((address_space(3))) void*)l, 16, 0, 0);
}
__device__ __forceinline__ bf16x8 ldlds(const char* p) {
    return __builtin_bit_cast(bf16x8, *(const u16x8*)p);
}

// ---------------- prep: weights fp32 -> bf16, + BN scale/shift ----------------
__global__ __launch_bounds__(256)
void prep_wb(const float* __restrict__ w1, const float* __restrict__ w2,
             const float* __restrict__ w3,
             unsigned short* __restrict__ o1, unsigned short* __restrict__ o2,
             unsigned short* __restrict__ o3,
             const float* b1, const float* g1, const float* be1, const float* m1, const float* v1,
             const float* b2, const float* g2, const float* be2, const float* m2, const float* v2,
             const float* b3, const float* g3, const float* be3, const float* m3, const float* v3,
             float* bn1, float* bn2, float* bn3)
{
    int i = blockIdx.x * 256 + threadIdx.x;
    const int n1 = 384 * 384 / 4, n2 = 768 * 768 / 4, n3 = 384 * 768 / 4;
    if (i < n1 + n2 + n3) {
        const float* src; unsigned short* dst; int j;
        if (i < n1)           { src = w1; dst = o1; j = i; }
        else if (i < n1 + n2) { src = w2; dst = o2; j = i - n1; }
        else                  { src = w3; dst = o3; j = i - n1 - n2; }
        float4 f = *(const float4*)(src + (size_t)j * 4);
        u16x4 pk = { f2bf(f.x), f2bf(f.y), f2bf(f.z), f2bf(f.w) };
        *(u16x4*)(dst + (size_t)j * 4) = pk;
    } else {
        int k = i - (n1 + n2 + n3);  // 0..1535
        const float *pb, *pg, *pbe, *pm, *pv; float* dst; int o, M;
        if (k < 384)       { pb=b1; pg=g1; pbe=be1; pm=m1; pv=v1; dst=bn1; o=k;        M=384; }
        else if (k < 1152) { pb=b2; pg=g2; pbe=be2; pm=m2; pv=v2; dst=bn2; o=k-384;    M=768; }
        else               { pb=b3; pg=g3; pbe=be3; pm=m3; pv=v3; dst=bn3; o=k-1152;   M=384; }
        float inv = pg[o] / sqrtf(pv[o] + EPSV);
        dst[o]     = inv;
        dst[M + o] = (pb[o] - pm[o]) * inv + pbe[o];
    }
}

// ---------------- prep: x [b][c][p] fp32 -> xT [bp][c] bf16 ----------------
__global__ __launch_bounds__(256)
void prep_xT(const float* __restrict__ x, unsigned short* __restrict__ xT)
{
    __shared__ float tl[64][65];
    const int t = threadIdx.x;
    const int c0 = blockIdx.x * 64;
    const int p0 = blockIdx.y * 64;
    const int b  = blockIdx.z;
    const float* xb = x + ((size_t)b * 384 + c0) * P_ + p0;
    {
        int c = t >> 2, j0 = (t & 3) * 16;
        #pragma unroll
        for (int j = 0; j < 16; j += 4) {
            float4 f4 = *(const float4*)(xb + (size_t)c * P_ + j0 + j);
            tl[c][j0 + j]     = f4.x; tl[c][j0 + j + 1] = f4.y;
            tl[c][j0 + j + 2] = f4.z; tl[c][j0 + j + 3] = f4.w;
        }
    }
    __syncthreads();
    {
        int p = t >> 2, c1 = (t & 3) * 16;
        unsigned short buf[16];
        #pragma unroll
        for (int j = 0; j < 16; ++j) buf[j] = f2bf(tl[c1 + j][p]);
        unsigned short* dst = xT + ((size_t)b * P_ + p0 + p) * 384 + c0 + c1;
        *(u16x8*)dst       = *(u16x8*)buf;
        *(u16x8*)(dst + 8) = *(u16x8*)(buf + 8);
    }
}

// ============ fine GEMM (r7 config): 128x128x64, 256 thr (4 waves 2x2, wave 64x64) ============
// A = W [MDIM][KD], B = In [NTOT][KD], both bf16 k-contig rows.
// LDS 64KB: buf d at d*32768 {A 16KB, B 16KB}; double-buffered, 2 blocks/CU.
// Counted loop: stage(kt+1) first, vmcnt(8) -> tile kt ready; never drains to 0.
// Rows 128B; 16B-granule swizzle key (row&7), inverse pre-applied to global source.
// EPI 0: BN -> bf16 [col][768]+o0.  EPI 1: +gelu.  EPI 2: BN+res -> fp32 [b][o][p].
template<int KD, int MDIM, int EPI>
__global__ __launch_bounds__(256, 2)
void gemmF(const unsigned short* __restrict__ W,
           const unsigned short* __restrict__ In,
           void* __restrict__ OutV,
           const float* __restrict__ bnp,
           const float* __restrict__ res)
{
    constexpr int NT = KD / 64;
    constexpr int MT = MDIM / 128;
    __shared__ __align__(16) char lds[65536];

    const int t    = threadIdx.x;
    const int lane = t & 63;
    const int wave = t >> 6;
    const int wm = wave >> 1, wn = wave & 1;
    const int fr = lane & 15, fg = lane >> 4;

    // bijective XCD chunk swizzle, M-fastest (MT consecutive wg share a B panel)
    const int nwg = gridDim.x;
    int id = blockIdx.x;
    int q = nwg >> 3, r = nwg & 7;
    int xcd = id & 7, pos = id >> 3;
    int wg = (xcd < r ? xcd * (q + 1) : r * (q + 1) + (xcd - r) * q) + pos;
    const int m0 = (wg % MT) * 128;
    const int n0 = (wg / MT) * 128;

    // ---- staging: 32KB/K-tile = 8 gloads of 4KB ----
    const int pcu  = (((t & 7) ^ ((t >> 3) & 7)) << 3); // swizzled source col (ushorts)
    const int srow = t >> 3;                             // 0..31
    const unsigned short* pA[4];
    const unsigned short* pB[4];
    #pragma unroll
    for (int i = 0; i < 4; ++i) {
        pA[i] = W  + (size_t)(m0 + i * 32 + srow) * KD + pcu;
        pB[i] = In + (size_t)(n0 + i * 32 + srow) * KD + pcu;
    }
    auto stage = [&](int kt) {
        int kk = (kt < NT ? kt : NT - 1) * 64;
        char* base = lds + (kt & 1) * 32768 + t * 16;
        #pragma unroll
        for (int i = 0; i < 4; ++i) gload16(pA[i] + kk, base + i * 4096);
        #pragma unroll
        for (int i = 0; i < 4; ++i) gload16(pB[i] + kk, base + 16384 + i * 4096);
    };

    const int ko0 = (fg * 16) ^ ((fr & 7) << 4);
    const int ko1 = (64 + fg * 16) ^ ((fr & 7) << 4);
    const int arow = wm * 64 + fr;
    const int brow = wn * 64 + fr;

    f32x4 acc[4][4] = {};

    stage(0);

    for (int kt = 0; kt < NT; ++kt) {
        stage(kt + 1);
        asm volatile("s_waitcnt vmcnt(8)" ::: "memory"); // tile kt fully in LDS
        __builtin_amdgcn_s_barrier();
        __builtin_amdgcn_sched_barrier(0);               // reads stay below barrier

        const char* base = lds + (kt & 1) * 32768;
        bf16x8 afr[4][2], bfr[4][2];
        #pragma unroll
        for (int mf = 0; mf < 4; ++mf) {
            afr[mf][0] = ldlds(base + (arow + mf * 16) * 128 + ko0);
            afr[mf][1] = ldlds(base + (arow + mf * 16) * 128 + ko1);
        }
        #pragma unroll
        for (int nf = 0; nf < 4; ++nf) {
            bfr[nf][0] = ldlds(base + 16384 + (brow + nf * 16) * 128 + ko0);
            bfr[nf][1] = ldlds(base + 16384 + (brow + nf * 16) * 128 + ko1);
        }
        // compiler inserts counted lgkmcnt before each dependent MFMA -> overlap
        #pragma unroll
        for (int ks = 0; ks < 2; ++ks)
            #pragma unroll
            for (int mf = 0; mf < 4; ++mf)
                #pragma unroll
                for (int nf = 0; nf < 4; ++nf)
                    acc[mf][nf] = __builtin_amdgcn_mfma_f32_16x16x32_bf16(
                        afr[mf][ks], bfr[nf][ks], acc[mf][nf], 0, 0, 0);
        asm volatile("s_waitcnt lgkmcnt(0)" ::: "memory"); // ~free: MFMAs consumed all
        __builtin_amdgcn_sched_barrier(0);
        __builtin_amdgcn_s_barrier(); // all waves done reading buf kt
    }

    // drain DMA + sync before overlaying LDS for the epilogue
    asm volatile("s_waitcnt vmcnt(0)" ::: "memory");
    __builtin_amdgcn_s_barrier();

    if (EPI < 2) {
        // [128 col][136 o-slot] u16 staging (row stride 272B -> 16B aligned)
        unsigned short* eL = (unsigned short*)lds;
        unsigned short* Out = (unsigned short*)OutV;
        #pragma unroll
        for (int mf = 0; mf < 4; ++mf) {
            const int o_l = wm * 64 + mf * 16 + fg * 4;
            f32x4 inv = *(const f32x4*)(bnp + m0 + o_l);
            f32x4 sh  = *(const f32x4*)(bnp + MDIM + m0 + o_l);
            #pragma unroll
            for (int nf = 0; nf < 4; ++nf) {
                const int col_l = wn * 64 + nf * 16 + fr;
                u16x4 pk;
                #pragma unroll
                for (int rr = 0; rr < 4; ++rr) {
                    float v = acc[mf][nf][rr] * inv[rr] + sh[rr];
                    if (EPI == 1) v = gelu_fast(v);
                    pk[rr] = f2bf(v);
                }
                *(u16x4*)(eL + col_l * 136 + o_l) = pk;
            }
        }
        __builtin_amdgcn_s_barrier();
        #pragma unroll
        for (int i = 0; i < 8; ++i) {
            const int col_l = (t >> 4) + i * 16;
            const int o8 = (t & 15) * 8;
            u16x8 v = *(const u16x8*)(eL + col_l * 136 + o8);
            *(u16x8*)(Out + (size_t)(n0 + col_l) * 768 + m0 + o8) = v;
        }
    } else {
        // two halves of [64 o][132 col] fp32 staging; coalesced dword IO
        float* eL = (float*)lds;
        float* Out = (float*)OutV;
        #pragma unroll
        for (int h = 0; h < 2; ++h) {
            if (wm == h) {
                #pragma unroll
                for (int mf = 0; mf < 4; ++mf) {
                    const int o_l = mf * 16 + fg * 4;
                    f32x4 inv = *(const f32x4*)(bnp + m0 + h * 64 + o_l);
                    f32x4 sh  = *(const f32x4*)(bnp + MDIM + m0 + h * 64 + o_l);
                    #pragma unroll
                    for (int nf = 0; nf < 4; ++nf) {
                        const int col_l = wn * 64 + nf * 16 + fr;
                        #pragma unroll
                        for (int rr = 0; rr < 4; ++rr)
                            eL[(o_l + rr) * 132 + col_l] =
                                acc[mf][nf][rr] * inv[rr] + sh[rr];
                    }
                }
            }
            __builtin_amdgcn_s_barrier();
            #pragma unroll
            for (int i = 0; i < 32; ++i) {
                const int idx = i * 256 + t;
                const int o_i = idx >> 7, col = idx & 127;
                const int col_g = n0 + col;
                const int b = col_g / P_;
                const int p = col_g - b * P_;
                const size_t adr = (size_t)b * 384 * P_ + (size_t)(m0 + h * 64 + o_i) * P_ + p;
                Out[adr] = eL[o_i * 132 + col] + res[adr];
            }
            __builtin_amdgcn_s_barrier();
        }
    }
}

// ============ fused mrconv: one block per (b, 8-channel group) ============
// Plane (3136 px x 8 ch) in LDS; col/row parity min1/min2 in-LDS; combine; write.
// y-half read once + written once. Grid (16 b, 48 cg): b-fastest so the
// 4 c-groups sharing a 64B line map to the same XCD's L2.
__global__ __launch_bounds__(256)
void mr_fused(unsigned short* __restrict__ y)
{
    __shared__ __align__(16) unsigned short pl[3136 * 8];   // [p][c] 49KB
    __shared__ float mins[4][2][56][8];                      // cm1,cm2,rm1,rm2 14KB
    const int t  = threadIdx.x;
    const int b  = blockIdx.x;
    const int c0 = blockIdx.y * 8;
    unsigned short* yb = y + (size_t)b * P_ * 768;

    for (int i = t; i < P_; i += 256)
        *(u16x8*)(pl + i * 8) = *(const u16x8*)(yb + (size_t)i * 768 + c0);
    __syncthreads();

    #pragma unroll
    for (int j = 0; j < 7; ++j) {               // 1792 tasks = 7 x 256
        const int id = j * 256 + t;
        const int c  = id & 7;
        const int qn = id >> 3;                  // 0..223
        const int isRow = qn >= 112;
        const int qq  = isRow ? qn - 112 : qn;
        const int par = qq >= 56 ? 1 : 0;
        const int idx = qq - par * 56;
        int p  = isRow ? idx * 56 + par : par * 56 + idx;
        const int st = isRow ? 2 : 112;
        float m1 = 3.4e38f, m2 = 3.4e38f;
        for (int k = 0; k < 28; ++k, p += st) {
            float v = bf2f(pl[p * 8 + c]);
            if (v < m1) { m2 = m1; m1 = v; } else if (v < m2) m2 = v;
        }
        const int ws = isRow ? 2 : 0;
        mins[ws][par][idx][c]     = m1;
        mins[ws + 1][par][idx][c] = m2;
    }
    __syncthreads();

    for (int i = t; i < P_; i += 256) {
        const int h = i / 56, w = i - h * 56;
        u16x8 vv = *(const u16x8*)(pl + i * 8);
        u16x8 out;
        #pragma unroll
        for (int c = 0; c < 8; ++c) {
            float v  = bf2f(vv[c]);
            float c1 = mins[0][h & 1][w][c];
            float c2 = mins[1][h & 1][w][c];
            float mh = v > c1 ? c1 : c2;
            float r1 = mins[2][w & 1][h][c];
            float r2 = mins[3][w & 1][h][c];
            float mw = v > r1 ? r1 : r2;
            out[c] = f2bf(fmaxf(0.0f, v - fminf(mh, mw)));
        }
        *(u16x8*)(yb + (size_t)i * 768 + 384 + c0) = out;
    }
}

extern "C" void kernel_launch(void* const* d_in, const int* in_sizes, int n_in,
                              void* d_out, int out_size, void* d_ws, size_t ws_size,
                              hipStream_t stream)
{
    const float* x      = (const float*)d_in[0];
    const float* fc1_w  = (const float*)d_in[1];
    const float* fc1_b  = (const float*)d_in[2];
    const float* fc1_g  = (const float*)d_in[3];
    const float* fc1_be = (const float*)d_in[4];
    const float* fc1_m  = (const float*)d_in[5];
    const float* fc1_v  = (const float*)d_in[6];
    const float* gc_w   = (const float*)d_in[7];
    const float* gc_b   = (const float*)d_in[8];
    const float* gc_g   = (const float*)d_in[9];
    const float* gc_be  = (const float*)d_in[10];
    const float* gc_m   = (const float*)d_in[11];
    const float* gc_v   = (const float*)d_in[12];
    const float* fc2_w  = (const float*)d_in[13];
    const float* fc2_b  = (const float*)d_in[14];
    const float* fc2_g  = (const float*)d_in[15];
    const float* fc2_be = (const float*)d_in[16];
    const float* fc2_m  = (const float*)d_in[17];
    const float* fc2_v  = (const float*)d_in[18];

    char* ws = (char*)d_ws;
    unsigned short* y   = (unsigned short*)ws;                       // [NTOT][768] bf16
    unsigned short* g   = y + (size_t)NTOT * 768;                    // [NTOT][768] bf16
    unsigned short* xT  = g + (size_t)NTOT * 768;                    // [NTOT][384] bf16
    unsigned short* wb1 = xT + (size_t)NTOT * 384;                   // [384][384]
    unsigned short* wb2 = wb1 + 384 * 384;                           // [768][768]
    unsigned short* wb3 = wb2 + 768 * 768;                           // [384][768]
    float* bn1 = (float*)(wb3 + 384 * 768);                          // [2][384]
    float* bn2 = bn1 + 2 * 384;                                      // [2][768]
    float* bn3 = bn2 + 2 * 768;                                      // [2][384]

    // weights->bf16 (1008 blocks) + BN fold (6 blocks)
    prep_wb<<<1014, 256, 0, stream>>>(fc1_w, gc_w, fc2_w, wb1, wb2, wb3,
                                      fc1_b, fc1_g, fc1_be, fc1_m, fc1_v,
                                      gc_b, gc_g, gc_be, gc_m, gc_v,
                                      fc2_b, fc2_g, fc2_be, fc2_m, fc2_v,
                                      bn1, bn2, bn3);
    prep_xT<<<dim3(6, 49, 16), 256, 0, stream>>>(x, xT);

    // y[:, 0:384] = bn(fc1 @ x)
    gemmF<384, 384, 0><<<dim3(3 * 392), 256, 0, stream>>>(wb1, xT, y, bn1, nullptr);
    // y[:, 384:768] = mrconv (single fused pass)
    mr_fused<<<dim3(16, 48), 256, 0, stream>>>(y);
    // g = gelu(bn(gc @ y))
    gemmF<768, 768, 1><<<dim3(6 * 392), 256, 0, stream>>>(wb2, y, g, bn2, nullptr);
    // out = bn(fc2 @ g) + x
    gemmF<768, 384, 2><<<dim3(3 * 392), 256, 0, stream>>>(wb3, g, (void*)d_out, bn3, x);
}

// Round 11
// 238.804 us; speedup vs baseline: 1.4946x; 1.0292x over previous
//
#include <hip/hip_runtime.h>

#define P_ 3136
#define NTOT 50176
#define EPSV 1e-5f

typedef __bf16 bf16x8 __attribute__((ext_vector_type(8)));
typedef float f32x4 __attribute__((ext_vector_type(4)));
typedef unsigned short u16x8 __attribute__((ext_vector_type(8)));
typedef unsigned short u16x4 __attribute__((ext_vector_type(4)));

__device__ __forceinline__ unsigned short f2bf(float f) {
    unsigned u = __builtin_bit_cast(unsigned, f);
    unsigned r = u + 0x7fffu + ((u >> 16) & 1u);
    return (unsigned short)(r >> 16);
}
__device__ __forceinline__ float bf2f(unsigned short h) {
    unsigned u = ((unsigned)h) << 16;
    return __builtin_bit_cast(float, u);
}
// tanh-approx GELU (max abs err ~1e-3; clamp avoids exp overflow NaN)
__device__ __forceinline__ float gelu_fast(float x) {
    float x2 = x * x;
    float u2 = x * (1.5957691216f + 0.0713548162f * x2);
    u2 = fminf(u2, 80.0f);
    float e = __expf(u2);
    return x * e * __builtin_amdgcn_rcpf(e + 1.0f);
}
__device__ __forceinline__ void gload16(const void* g, void* l) {
    __builtin_amdgcn_global_load_lds(
        (const __attribute__((address_space(1))) void*)g,
        (__attribute__((address_space(3))) void*)l, 16, 0, 0);
}
__device__ __forceinline__ bf16x8 ldlds(const char* p) {
    return __builtin_bit_cast(bf16x8, *(const u16x8*)p);
}

// ---------------- prep: weights fp32 -> bf16, + BN scale/shift ----------------
__global__ __launch_bounds__(256)
void prep_wb(const float* __restrict__ w1, const float* __restrict__ w2,
             const float* __restrict__ w3,
             unsigned short* __restrict__ o1, unsigned short* __restrict__ o2,
             unsigned short* __restrict__ o3,
             const float* b1, const float* g1, const float* be1, const float* m1, const float* v1,
             const float* b2, const float* g2, const float* be2, const float* m2, const float* v2,
             const float* b3, const float* g3, const float* be3, const float* m3, const float* v3,
             float* bn1, float* bn2, float* bn3)
{
    int i = blockIdx.x * 256 + threadIdx.x;
    const int n1 = 384 * 384 / 4, n2 = 768 * 768 / 4, n3 = 384 * 768 / 4;
    if (i < n1 + n2 + n3) {
        const float* src; unsigned short* dst; int j;
        if (i < n1)           { src = w1; dst = o1; j = i; }
        else if (i < n1 + n2) { src = w2; dst = o2; j = i - n1; }
        else                  { src = w3; dst = o3; j = i - n1 - n2; }
        float4 f = *(const float4*)(src + (size_t)j * 4);
        u16x4 pk = { f2bf(f.x), f2bf(f.y), f2bf(f.z), f2bf(f.w) };
        *(u16x4*)(dst + (size_t)j * 4) = pk;
    } else {
        int k = i - (n1 + n2 + n3);  // 0..1535
        const float *pb, *pg, *pbe, *pm, *pv; float* dst; int o, M;
        if (k < 384)       { pb=b1; pg=g1; pbe=be1; pm=m1; pv=v1; dst=bn1; o=k;        M=384; }
        else if (k < 1152) { pb=b2; pg=g2; pbe=be2; pm=m2; pv=v2; dst=bn2; o=k-384;    M=768; }
        else               { pb=b3; pg=g3; pbe=be3; pm=m3; pv=v3; dst=bn3; o=k-1152;   M=384; }
        float inv = pg[o] / sqrtf(pv[o] + EPSV);
        dst[o]     = inv;
        dst[M + o] = (pb[o] - pm[o]) * inv + pbe[o];
    }
}

// ---------------- prep: x [b][c][p] fp32 -> xT [bp][c] bf16 ----------------
__global__ __launch_bounds__(256)
void prep_xT(const float* __restrict__ x, unsigned short* __restrict__ xT)
{
    __shared__ float tl[64][65];
    const int t = threadIdx.x;
    const int c0 = blockIdx.x * 64;
    const int p0 = blockIdx.y * 64;
    const int b  = blockIdx.z;
    const float* xb = x + ((size_t)b * 384 + c0) * P_ + p0;
    {
        int c = t >> 2, j0 = (t & 3) * 16;
        #pragma unroll
        for (int j = 0; j < 16; j += 4) {
            float4 f4 = *(const float4*)(xb + (size_t)c * P_ + j0 + j);
            tl[c][j0 + j]     = f4.x; tl[c][j0 + j + 1] = f4.y;
            tl[c][j0 + j + 2] = f4.z; tl[c][j0 + j + 3] = f4.w;
        }
    }
    __syncthreads();
    {
        int p = t >> 2, c1 = (t & 3) * 16;
        unsigned short buf[16];
        #pragma unroll
        for (int j = 0; j < 16; ++j) buf[j] = f2bf(tl[c1 + j][p]);
        unsigned short* dst = xT + ((size_t)b * P_ + p0 + p) * 384 + c0 + c1;
        *(u16x8*)dst       = *(u16x8*)buf;
        *(u16x8*)(dst + 8) = *(u16x8*)(buf + 8);
    }
}

// ============ fine GEMM: 128x128x64, 256 thr (4 waves 2x2, wave 64x64) ============
// A = W [MDIM][KD], B = In [NTOT][KD], both bf16 k-contig rows.
// LDS 64KB: buf d at d*32768 {A 16KB, B 16KB}; double-buffered, 2 blocks/CU.
// SINGLE barrier per K-tile: [vmcnt(0); barrier; stage(kt+1); reads; MFMA].
// Safe because reaching barrier(kt) implies all waves' tile-(kt-1) ds_reads
// completed (compiler lgkmcnt before MFMA), so DMA into buf[(kt+1)&1] issued
// after the barrier cannot clobber in-flight reads.
// Rows 128B; 16B-granule swizzle key (row&7), inverse pre-applied to global source.
// EPI 0: BN -> bf16 [col][768]+o0.  EPI 1: +gelu.  EPI 2: BN+res -> fp32 [b][o][p].
template<int KD, int MDIM, int EPI>
__global__ __launch_bounds__(256, 2)
void gemmF(const unsigned short* __restrict__ W,
           const unsigned short* __restrict__ In,
           void* __restrict__ OutV,
           const float* __restrict__ bnp,
           const float* __restrict__ res)
{
    constexpr int NT = KD / 64;
    constexpr int MT = MDIM / 128;
    __shared__ __align__(16) char lds[65536];

    const int t    = threadIdx.x;
    const int lane = t & 63;
    const int wave = t >> 6;
    const int wm = wave >> 1, wn = wave & 1;
    const int fr = lane & 15, fg = lane >> 4;

    // bijective XCD chunk swizzle, M-fastest (MT consecutive wg share a B panel)
    const int nwg = gridDim.x;
    int id = blockIdx.x;
    int q = nwg >> 3, r = nwg & 7;
    int xcd = id & 7, pos = id >> 3;
    int wg = (xcd < r ? xcd * (q + 1) : r * (q + 1) + (xcd - r) * q) + pos;
    const int m0 = (wg % MT) * 128;
    const int n0 = (wg / MT) * 128;

    // ---- staging: 32KB/K-tile = 8 gloads of 4KB ----
    const int pcu  = (((t & 7) ^ ((t >> 3) & 7)) << 3); // swizzled source col (ushorts)
    const int srow = t >> 3;                             // 0..31
    const unsigned short* pA[4];
    const unsigned short* pB[4];
    #pragma unroll
    for (int i = 0; i < 4; ++i) {
        pA[i] = W  + (size_t)(m0 + i * 32 + srow) * KD + pcu;
        pB[i] = In + (size_t)(n0 + i * 32 + srow) * KD + pcu;
    }
    auto stage = [&](int kt) {
        int kk = kt * 64;
        char* base = lds + (kt & 1) * 32768 + t * 16;
        #pragma unroll
        for (int i = 0; i < 4; ++i) gload16(pA[i] + kk, base + i * 4096);
        #pragma unroll
        for (int i = 0; i < 4; ++i) gload16(pB[i] + kk, base + 16384 + i * 4096);
    };

    const int ko0 = (fg * 16) ^ ((fr & 7) << 4);
    const int ko1 = (64 + fg * 16) ^ ((fr & 7) << 4);
    const int arow = wm * 64 + fr;
    const int brow = wn * 64 + fr;

    f32x4 acc[4][4] = {};

    stage(0);

    for (int kt = 0; kt < NT; ++kt) {
        asm volatile("s_waitcnt vmcnt(0)" ::: "memory"); // own stage(kt) complete
        __builtin_amdgcn_s_barrier();                    // all waves: buf[kt&1] ready,
                                                         // buf[(kt+1)&1] fully consumed
        __builtin_amdgcn_sched_barrier(0);
        if (kt + 1 < NT) stage(kt + 1);                  // DMA into the other buffer
        __builtin_amdgcn_sched_barrier(0);

        const char* base = lds + (kt & 1) * 32768;
        bf16x8 afr[4][2], bfr[4][2];
        #pragma unroll
        for (int mf = 0; mf < 4; ++mf) {
            afr[mf][0] = ldlds(base + (arow + mf * 16) * 128 + ko0);
            afr[mf][1] = ldlds(base + (arow + mf * 16) * 128 + ko1);
        }
        #pragma unroll
        for (int nf = 0; nf < 4; ++nf) {
            bfr[nf][0] = ldlds(base + 16384 + (brow + nf * 16) * 128 + ko0);
            bfr[nf][1] = ldlds(base + 16384 + (brow + nf * 16) * 128 + ko1);
        }
        // compiler interleaves counted lgkmcnt ds_reads with MFMAs
        #pragma unroll
        for (int ks = 0; ks < 2; ++ks)
            #pragma unroll
            for (int mf = 0; mf < 4; ++mf)
                #pragma unroll
                for (int nf = 0; nf < 4; ++nf)
                    acc[mf][nf] = __builtin_amdgcn_mfma_f32_16x16x32_bf16(
                        afr[mf][ks], bfr[nf][ks], acc[mf][nf], 0, 0, 0);
    }

    // sync before overlaying LDS for the epilogue
    asm volatile("s_waitcnt vmcnt(0)" ::: "memory");
    __builtin_amdgcn_s_barrier();

    if (EPI < 2) {
        // [128 col][136 o-slot] u16 staging (row stride 272B -> 16B aligned)
        unsigned short* eL = (unsigned short*)lds;
        unsigned short* Out = (unsigned short*)OutV;
        #pragma unroll
        for (int mf = 0; mf < 4; ++mf) {
            const int o_l = wm * 64 + mf * 16 + fg * 4;
            f32x4 inv = *(const f32x4*)(bnp + m0 + o_l);
            f32x4 sh  = *(const f32x4*)(bnp + MDIM + m0 + o_l);
            #pragma unroll
            for (int nf = 0; nf < 4; ++nf) {
                const int col_l = wn * 64 + nf * 16 + fr;
                u16x4 pk;
                #pragma unroll
                for (int rr = 0; rr < 4; ++rr) {
                    float v = acc[mf][nf][rr] * inv[rr] + sh[rr];
                    if (EPI == 1) v = gelu_fast(v);
                    pk[rr] = f2bf(v);
                }
                *(u16x4*)(eL + col_l * 136 + o_l) = pk;
            }
        }
        __builtin_amdgcn_s_barrier();
        #pragma unroll
        for (int i = 0; i < 8; ++i) {
            const int col_l = (t >> 4) + i * 16;
            const int o8 = (t & 15) * 8;
            u16x8 v = *(const u16x8*)(eL + col_l * 136 + o8);
            *(u16x8*)(Out + (size_t)(n0 + col_l) * 768 + m0 + o8) = v;
        }
    } else {
        // two halves of [64 o][132 col] fp32 staging; coalesced dword IO
        float* eL = (float*)lds;
        float* Out = (float*)OutV;
        #pragma unroll
        for (int h = 0; h < 2; ++h) {
            if (wm == h) {
                #pragma unroll
                for (int mf = 0; mf < 4; ++mf) {
                    const int o_l = mf * 16 + fg * 4;
                    f32x4 inv = *(const f32x4*)(bnp + m0 + h * 64 + o_l);
                    f32x4 sh  = *(const f32x4*)(bnp + MDIM + m0 + h * 64 + o_l);
                    #pragma unroll
                    for (int nf = 0; nf < 4; ++nf) {
                        const int col_l = wn * 64 + nf * 16 + fr;
                        #pragma unroll
                        for (int rr = 0; rr < 4; ++rr)
                            eL[(o_l + rr) * 132 + col_l] =
                                acc[mf][nf][rr] * inv[rr] + sh[rr];
                    }
                }
            }
            __builtin_amdgcn_s_barrier();
            #pragma unroll
            for (int i = 0; i < 32; ++i) {
                const int idx = i * 256 + t;
                const int o_i = idx >> 7, col = idx & 127;
                const int col_g = n0 + col;
                const int b = col_g / P_;
                const int p = col_g - b * P_;
                const size_t adr = (size_t)b * 384 * P_ + (size_t)(m0 + h * 64 + o_i) * P_ + p;
                Out[adr] = eL[o_i * 132 + col] + res[adr];
            }
            __builtin_amdgcn_s_barrier();
        }
    }
}

// ---------------- mrconv pass 1: per-(b, w|h) parity mins ----------------
#define MINSEG (16 * 2 * 56 * 384)
__global__ __launch_bounds__(384)
void mr_min(const unsigned short* __restrict__ y, float* __restrict__ mins)
{
    const int c = threadIdx.x;
    const int q = blockIdx.x;
    const int b = blockIdx.y;
    const unsigned short* yb = y + (size_t)b * P_ * 768;
    float m1e = 3.4e38f, m2e = 3.4e38f, m1o = 3.4e38f, m2o = 3.4e38f;
    if (q < 56) {
        int w = q;
        for (int h = 0; h < 56; h += 2) {
            float v0 = bf2f(yb[(size_t)(h * 56 + w) * 768 + c]);
            float v1 = bf2f(yb[(size_t)((h + 1) * 56 + w) * 768 + c]);
            if (v0 < m1e) { m2e = m1e; m1e = v0; } else if (v0 < m2e) m2e = v0;
            if (v1 < m1o) { m2o = m1o; m1o = v1; } else if (v1 < m2o) m2o = v1;
        }
        float* cm1 = mins;
        float* cm2 = mins + MINSEG;
        cm1[((b * 2 + 0) * 56 + w) * 384 + c] = m1e;
        cm1[((b * 2 + 1) * 56 + w) * 384 + c] = m1o;
        cm2[((b * 2 + 0) * 56 + w) * 384 + c] = m2e;
        cm2[((b * 2 + 1) * 56 + w) * 384 + c] = m2o;
    } else {
        int h = q - 56;
        for (int w = 0; w < 56; w += 2) {
            float v0 = bf2f(yb[(size_t)(h * 56 + w) * 768 + c]);
            float v1 = bf2f(yb[(size_t)(h * 56 + w + 1) * 768 + c]);
            if (v0 < m1e) { m2e = m1e; m1e = v0; } else if (v0 < m2e) m2e = v0;
            if (v1 < m1o) { m2o = m1o; m1o = v1; } else if (v1 < m2o) m2o = v1;
        }
        float* rm1 = mins + 2 * MINSEG;
        float* rm2 = mins + 3 * MINSEG;
        rm1[((b * 2 + 0) * 56 + h) * 384 + c] = m1e;
        rm1[((b * 2 + 1) * 56 + h) * 384 + c] = m1o;
        rm2[((b * 2 + 0) * 56 + h) * 384 + c] = m2e;
        rm2[((b * 2 + 1) * 56 + h) * 384 + c] = m2o;
    }
}

// ---------------- mrconv pass 2: combine -> y[:, 384:768] ----------------
__global__ __launch_bounds__(384)
void mr_comb(unsigned short* __restrict__ y, const float* __restrict__ mins)
{
    const int c = threadIdx.x;
    const int h = blockIdx.x;
    const int b = blockIdx.y;
    unsigned short* yb = y + (size_t)b * P_ * 768;
    const float* cm1 = mins;
    const float* cm2 = mins + MINSEG;
    const float* rm1 = mins + 2 * MINSEG;
    const float* rm2 = mins + 3 * MINSEG;
    const int parh = h & 1;
    float r1e = rm1[((b * 2 + 0) * 56 + h) * 384 + c];
    float r2e = rm2[((b * 2 + 0) * 56 + h) * 384 + c];
    float r1o = rm1[((b * 2 + 1) * 56 + h) * 384 + c];
    float r2o = rm2[((b * 2 + 1) * 56 + h) * 384 + c];
    #pragma unroll 2
    for (int w = 0; w < 56; ++w) {
        float v  = bf2f(yb[(size_t)(h * 56 + w) * 768 + c]);
        float c1 = cm1[((b * 2 + parh) * 56 + w) * 384 + c];
        float c2 = cm2[((b * 2 + parh) * 56 + w) * 384 + c];
        float mh = v > c1 ? c1 : c2;
        float rw1 = (w & 1) ? r1o : r1e;
        float rw2 = (w & 1) ? r2o : r2e;
        float mw = v > rw1 ? rw1 : rw2;
        float xj = fmaxf(0.0f, v - fminf(mh, mw));
        yb[(size_t)(h * 56 + w) * 768 + 384 + c] = f2bf(xj);
    }
}

extern "C" void kernel_launch(void* const* d_in, const int* in_sizes, int n_in,
                              void* d_out, int out_size, void* d_ws, size_t ws_size,
                              hipStream_t stream)
{
    const float* x      = (const float*)d_in[0];
    const float* fc1_w  = (const float*)d_in[1];
    const float* fc1_b  = (const float*)d_in[2];
    const float* fc1_g  = (const float*)d_in[3];
    const float* fc1_be = (const float*)d_in[4];
    const float* fc1_m  = (const float*)d_in[5];
    const float* fc1_v  = (const float*)d_in[6];
    const float* gc_w   = (const float*)d_in[7];
    const float* gc_b   = (const float*)d_in[8];
    const float* gc_g   = (const float*)d_in[9];
    const float* gc_be  = (const float*)d_in[10];
    const float* gc_m   = (const float*)d_in[11];
    const float* gc_v   = (const float*)d_in[12];
    const float* fc2_w  = (const float*)d_in[13];
    const float* fc2_b  = (const float*)d_in[14];
    const float* fc2_g  = (const float*)d_in[15];
    const float* fc2_be = (const float*)d_in[16];
    const float* fc2_m  = (const float*)d_in[17];
    const float* fc2_v  = (const float*)d_in[18];

    char* ws = (char*)d_ws;
    unsigned short* y   = (unsigned short*)ws;                       // [NTOT][768] bf16
    unsigned short* g   = y + (size_t)NTOT * 768;                    // [NTOT][768] bf16
    unsigned short* xT  = g + (size_t)NTOT * 768;                    // [NTOT][384] bf16
    unsigned short* wb1 = xT + (size_t)NTOT * 384;                   // [384][384]
    unsigned short* wb2 = wb1 + 384 * 384;                           // [768][768]
    unsigned short* wb3 = wb2 + 768 * 768;                           // [384][768]
    float* bn1 = (float*)(wb3 + 384 * 768);                          // [2][384]
    float* bn2 = bn1 + 2 * 384;                                      // [2][768]
    float* bn3 = bn2 + 2 * 768;                                      // [2][384]
    float* mins = bn3 + 2 * 384;                                     // 4 * MINSEG

    // weights->bf16 (1008 blocks) + BN fold (6 blocks)
    prep_wb<<<1014, 256, 0, stream>>>(fc1_w, gc_w, fc2_w, wb1, wb2, wb3,
                                      fc1_b, fc1_g, fc1_be, fc1_m, fc1_v,
                                      gc_b, gc_g, gc_be, gc_m, gc_v,
                                      fc2_b, fc2_g, fc2_be, fc2_m, fc2_v,
                                      bn1, bn2, bn3);
    prep_xT<<<dim3(6, 49, 16), 256, 0, stream>>>(x, xT);

    // y[:, 0:384] = bn(fc1 @ x)
    gemmF<384, 384, 0><<<dim3(3 * 392), 256, 0, stream>>>(wb1, xT, y, bn1, nullptr);
    // y[:, 384:768] = mrconv (two-pass, coalesced)
    mr_min<<<dim3(112, 16), 384, 0, stream>>>(y, mins);
    mr_comb<<<dim3(56, 16), 384, 0, stream>>>(y, mins);
    // g = gelu(bn(gc @ y))
    gemmF<768, 768, 1><<<dim3(6 * 392), 256, 0, stream>>>(wb2, y, g, bn2, nullptr);
    // out = bn(fc2 @ g) + x
    gemmF<768, 384, 2><<<dim3(3 * 392), 256, 0, stream>>>(wb3, g, (void*)d_out, bn3, x);
}

// Round 12
// 236.761 us; speedup vs baseline: 1.5075x; 1.0086x over previous
//
#include <hip/hip_runtime.h>

#define P_ 3136
#define NTOT 50176
#define EPSV 1e-5f

typedef __bf16 bf16x8 __attribute__((ext_vector_type(8)));
typedef float f32x4 __attribute__((ext_vector_type(4)));
typedef unsigned short u16x8 __attribute__((ext_vector_type(8)));
typedef unsigned short u16x4 __attribute__((ext_vector_type(4)));

__device__ __forceinline__ unsigned short f2bf(float f) {
    unsigned u = __builtin_bit_cast(unsigned, f);
    unsigned r = u + 0x7fffu + ((u >> 16) & 1u);
    return (unsigned short)(r >> 16);
}
__device__ __forceinline__ float bf2f(unsigned short h) {
    unsigned u = ((unsigned)h) << 16;
    return __builtin_bit_cast(float, u);
}
// tanh-approx GELU (max abs err ~1e-3; clamp avoids exp overflow NaN)
__device__ __forceinline__ float gelu_fast(float x) {
    float x2 = x * x;
    float u2 = x * (1.5957691216f + 0.0713548162f * x2);
    u2 = fminf(u2, 80.0f);
    float e = __expf(u2);
    return x * e * __builtin_amdgcn_rcpf(e + 1.0f);
}
__device__ __forceinline__ void gload16(const void* g, void* l) {
    __builtin_amdgcn_global_load_lds(
        (const __attribute__((address_space(1))) void*)g,
        (__attribute__((address_space(3))) void*)l, 16, 0, 0);
}
__device__ __forceinline__ bf16x8 ldlds(const char* p) {
    return __builtin_bit_cast(bf16x8, *(const u16x8*)p);
}

// ---------------- prep: weights fp32 -> bf16, + BN scale/shift ----------------
__global__ __launch_bounds__(256)
void prep_wb(const float* __restrict__ w1, const float* __restrict__ w2,
             const float* __restrict__ w3,
             unsigned short* __restrict__ o1, unsigned short* __restrict__ o2,
             unsigned short* __restrict__ o3,
             const float* b1, const float* g1, const float* be1, const float* m1, const float* v1,
             const float* b2, const float* g2, const float* be2, const float* m2, const float* v2,
             const float* b3, const float* g3, const float* be3, const float* m3, const float* v3,
             float* bn1, float* bn2, float* bn3)
{
    int i = blockIdx.x * 256 + threadIdx.x;
    const int n1 = 384 * 384 / 4, n2 = 768 * 768 / 4, n3 = 384 * 768 / 4;
    if (i < n1 + n2 + n3) {
        const float* src; unsigned short* dst; int j;
        if (i < n1)           { src = w1; dst = o1; j = i; }
        else if (i < n1 + n2) { src = w2; dst = o2; j = i - n1; }
        else                  { src = w3; dst = o3; j = i - n1 - n2; }
        float4 f = *(const float4*)(src + (size_t)j * 4);
        u16x4 pk = { f2bf(f.x), f2bf(f.y), f2bf(f.z), f2bf(f.w) };
        *(u16x4*)(dst + (size_t)j * 4) = pk;
    } else {
        int k = i - (n1 + n2 + n3);  // 0..1535
        const float *pb, *pg, *pbe, *pm, *pv; float* dst; int o, M;
        if (k < 384)       { pb=b1; pg=g1; pbe=be1; pm=m1; pv=v1; dst=bn1; o=k;        M=384; }
        else if (k < 1152) { pb=b2; pg=g2; pbe=be2; pm=m2; pv=v2; dst=bn2; o=k-384;    M=768; }
        else               { pb=b3; pg=g3; pbe=be3; pm=m3; pv=v3; dst=bn3; o=k-1152;   M=384; }
        float inv = pg[o] / sqrtf(pv[o] + EPSV);
        dst[o]     = inv;
        dst[M + o] = (pb[o] - pm[o]) * inv + pbe[o];
    }
}

// ---------------- prep: x [b][c][p] fp32 -> xT [bp][c] bf16 ----------------
__global__ __launch_bounds__(256)
void prep_xT(const float* __restrict__ x, unsigned short* __restrict__ xT)
{
    __shared__ float tl[64][65];
    const int t = threadIdx.x;
    const int c0 = blockIdx.x * 64;
    const int p0 = blockIdx.y * 64;
    const int b  = blockIdx.z;
    const float* xb = x + ((size_t)b * 384 + c0) * P_ + p0;
    {
        int c = t >> 2, j0 = (t & 3) * 16;
        #pragma unroll
        for (int j = 0; j < 16; j += 4) {
            float4 f4 = *(const float4*)(xb + (size_t)c * P_ + j0 + j);
            tl[c][j0 + j]     = f4.x; tl[c][j0 + j + 1] = f4.y;
            tl[c][j0 + j + 2] = f4.z; tl[c][j0 + j + 3] = f4.w;
        }
    }
    __syncthreads();
    {
        int p = t >> 2, c1 = (t & 3) * 16;
        unsigned short buf[16];
        #pragma unroll
        for (int j = 0; j < 16; ++j) buf[j] = f2bf(tl[c1 + j][p]);
        unsigned short* dst = xT + ((size_t)b * P_ + p0 + p) * 384 + c0 + c1;
        *(u16x8*)dst       = *(u16x8*)buf;
        *(u16x8*)(dst + 8) = *(u16x8*)(buf + 8);
    }
}

// ============ shared GEMM body: 128x128x64, 256 thr (4 waves 2x2, wave 64x64) ============
// A = W [MDIM][KD], B = In [NTOT][KD], both bf16 k-contig rows.
// LDS 64KB: buf d at d*32768 {A 16KB, B 16KB}; double-buffered, 2 blocks/CU.
// Single barrier per K-tile: [vmcnt(0); barrier; stage(kt+1); reads; MFMA].
// Rows 128B; 16B-granule swizzle key (row&7), inverse pre-applied to global source.
// EPI 0: BN -> bf16 [col][768]+o0.  EPI 1: +gelu.  EPI 2: BN+res -> fp32 [b][o][p],
//   single-phase full-LDS fp32 stage + division-free pipelined res/store loop.
template<int KD, int MDIM, int EPI>
__device__ __forceinline__ void gemm_body(
    const unsigned short* __restrict__ W,
    const unsigned short* __restrict__ In,
    void* __restrict__ OutV,
    const float* __restrict__ bnp,
    const float* __restrict__ res,
    char* lds)
{
    constexpr int NT = KD / 64;
    constexpr int MT = MDIM / 128;

    const int t    = threadIdx.x;
    const int lane = t & 63;
    const int wave = t >> 6;
    const int wm = wave >> 1, wn = wave & 1;
    const int fr = lane & 15, fg = lane >> 4;

    // bijective XCD chunk swizzle, M-fastest (MT consecutive wg share a B panel)
    const int nwg = gridDim.x;
    int id = blockIdx.x;
    int q = nwg >> 3, r = nwg & 7;
    int xcd = id & 7, pos = id >> 3;
    int wg = (xcd < r ? xcd * (q + 1) : r * (q + 1) + (xcd - r) * q) + pos;
    const int m0 = (wg % MT) * 128;
    const int n0 = (wg / MT) * 128;

    // ---- staging: 32KB/K-tile = 8 gloads of 4KB ----
    const int pcu  = (((t & 7) ^ ((t >> 3) & 7)) << 3); // swizzled source col (ushorts)
    const int srow = t >> 3;                             // 0..31
    const unsigned short* pA[4];
    const unsigned short* pB[4];
    #pragma unroll
    for (int i = 0; i < 4; ++i) {
        pA[i] = W  + (size_t)(m0 + i * 32 + srow) * KD + pcu;
        pB[i] = In + (size_t)(n0 + i * 32 + srow) * KD + pcu;
    }
    auto stage = [&](int kt) {
        int kk = kt * 64;
        char* base = lds + (kt & 1) * 32768 + t * 16;
        #pragma unroll
        for (int i = 0; i < 4; ++i) gload16(pA[i] + kk, base + i * 4096);
        #pragma unroll
        for (int i = 0; i < 4; ++i) gload16(pB[i] + kk, base + 16384 + i * 4096);
    };

    const int ko0 = (fg * 16) ^ ((fr & 7) << 4);
    const int ko1 = (64 + fg * 16) ^ ((fr & 7) << 4);
    const int arow = wm * 64 + fr;
    const int brow = wn * 64 + fr;

    f32x4 acc[4][4] = {};

    stage(0);

    for (int kt = 0; kt < NT; ++kt) {
        asm volatile("s_waitcnt vmcnt(0)" ::: "memory"); // own stage(kt) complete
        __builtin_amdgcn_s_barrier();                    // buf[kt&1] ready; other consumed
        __builtin_amdgcn_sched_barrier(0);
        if (kt + 1 < NT) stage(kt + 1);                  // DMA into the other buffer
        __builtin_amdgcn_sched_barrier(0);

        const char* base = lds + (kt & 1) * 32768;
        bf16x8 afr[4][2], bfr[4][2];
        #pragma unroll
        for (int mf = 0; mf < 4; ++mf) {
            afr[mf][0] = ldlds(base + (arow + mf * 16) * 128 + ko0);
            afr[mf][1] = ldlds(base + (arow + mf * 16) * 128 + ko1);
        }
        #pragma unroll
        for (int nf = 0; nf < 4; ++nf) {
            bfr[nf][0] = ldlds(base + 16384 + (brow + nf * 16) * 128 + ko0);
            bfr[nf][1] = ldlds(base + 16384 + (brow + nf * 16) * 128 + ko1);
        }
        #pragma unroll
        for (int ks = 0; ks < 2; ++ks)
            #pragma unroll
            for (int mf = 0; mf < 4; ++mf)
                #pragma unroll
                for (int nf = 0; nf < 4; ++nf)
                    acc[mf][nf] = __builtin_amdgcn_mfma_f32_16x16x32_bf16(
                        afr[mf][ks], bfr[nf][ks], acc[mf][nf], 0, 0, 0);
    }

    // sync before overlaying LDS for the epilogue
    asm volatile("s_waitcnt vmcnt(0)" ::: "memory");
    __builtin_amdgcn_s_barrier();

    if (EPI < 2) {
        // [128 col][136 o-slot] u16 staging (row stride 272B -> 16B aligned)
        unsigned short* eL = (unsigned short*)lds;
        unsigned short* Out = (unsigned short*)OutV;
        #pragma unroll
        for (int mf = 0; mf < 4; ++mf) {
            const int o_l = wm * 64 + mf * 16 + fg * 4;
            f32x4 inv = *(const f32x4*)(bnp + m0 + o_l);
            f32x4 sh  = *(const f32x4*)(bnp + MDIM + m0 + o_l);
            #pragma unroll
            for (int nf = 0; nf < 4; ++nf) {
                const int col_l = wn * 64 + nf * 16 + fr;
                u16x4 pk;
                #pragma unroll
                for (int rr = 0; rr < 4; ++rr) {
                    float v = acc[mf][nf][rr] * inv[rr] + sh[rr];
                    if (EPI == 1) v = gelu_fast(v);
                    pk[rr] = f2bf(v);
                }
                *(u16x4*)(eL + col_l * 136 + o_l) = pk;
            }
        }
        __builtin_amdgcn_s_barrier();
        #pragma unroll
        for (int i = 0; i < 8; ++i) {
            const int col_l = (t >> 4) + i * 16;
            const int o8 = (t & 15) * 8;
            u16x8 v = *(const u16x8*)(eL + col_l * 136 + o8);
            *(u16x8*)(Out + (size_t)(n0 + col_l) * 768 + m0 + o8) = v;
        }
    } else {
        // single-phase [128 o][128 col] fp32 staging (exactly 64KB); all waves write.
        float* eL = (float*)lds;
        float* Out = (float*)OutV;
        #pragma unroll
        for (int mf = 0; mf < 4; ++mf) {
            const int o_l = wm * 64 + mf * 16 + fg * 4;
            f32x4 inv = *(const f32x4*)(bnp + m0 + o_l);
            f32x4 sh  = *(const f32x4*)(bnp + MDIM + m0 + o_l);
            #pragma unroll
            for (int nf = 0; nf < 4; ++nf) {
                const int col_l = wn * 64 + nf * 16 + fr;
                #pragma unroll
                for (int rr = 0; rr < 4; ++rr)
                    eL[(o_l + rr) * 128 + col_l] = acc[mf][nf][rr] * inv[rr] + sh[rr];
            }
        }
        __builtin_amdgcn_s_barrier();
        // division-free batch/pixel decomposition: block spans cols [n0, n0+128)
        const int b0 = n0 / P_;            // one block-uniform division
        const int r0 = n0 - b0 * P_;
        // 8 groups x 8-deep pipelined {res load, LDS read} -> {store}
        #pragma unroll
        for (int g8 = 0; g8 < 8; ++g8) {
            size_t adr[8]; float ev[8], rv[8];
            #pragma unroll
            for (int u = 0; u < 8; ++u) {
                const int idx = (g8 * 8 + u) * 256 + t;
                const int o_i = idx >> 7, col = idx & 127;
                int p = r0 + col;
                const int wrap = p >= P_;
                p -= wrap ? P_ : 0;
                adr[u] = (size_t)(b0 + wrap) * 384 * P_ + (size_t)(m0 + o_i) * P_ + p;
                ev[u]  = eL[o_i * 128 + col];
                rv[u]  = res[adr[u]];
            }
            #pragma unroll
            for (int u = 0; u < 8; ++u)
                Out[adr[u]] = ev[u] + rv[u];
        }
    }
}

__global__ __launch_bounds__(256, 2)
void gemm1(const unsigned short* __restrict__ W, const unsigned short* __restrict__ In,
           void* __restrict__ OutV, const float* __restrict__ bnp)
{
    __shared__ __align__(16) char lds[65536];
    gemm_body<384, 384, 0>(W, In, OutV, bnp, nullptr, lds);
}
__global__ __launch_bounds__(256, 2)
void gemm2(const unsigned short* __restrict__ W, const unsigned short* __restrict__ In,
           void* __restrict__ OutV, const float* __restrict__ bnp)
{
    __shared__ __align__(16) char lds[65536];
    gemm_body<768, 768, 1>(W, In, OutV, bnp, nullptr, lds);
}
__global__ __launch_bounds__(256, 2)
void gemm3(const unsigned short* __restrict__ W, const unsigned short* __restrict__ In,
           void* __restrict__ OutV, const float* __restrict__ bnp,
           const float* __restrict__ res)
{
    __shared__ __align__(16) char lds[65536];
    gemm_body<768, 384, 2>(W, In, OutV, bnp, res, lds);
}

// ---------------- mrconv pass 1: per-(b, w|h) parity mins ----------------
#define MINSEG (16 * 2 * 56 * 384)
__global__ __launch_bounds__(384)
void mr_min(const unsigned short* __restrict__ y, float* __restrict__ mins)
{
    const int c = threadIdx.x;
    const int q = blockIdx.x;
    const int b = blockIdx.y;
    const unsigned short* yb = y + (size_t)b * P_ * 768;
    float m1e = 3.4e38f, m2e = 3.4e38f, m1o = 3.4e38f, m2o = 3.4e38f;
    if (q < 56) {
        int w = q;
        for (int h = 0; h < 56; h += 2) {
            float v0 = bf2f(yb[(size_t)(h * 56 + w) * 768 + c]);
            float v1 = bf2f(yb[(size_t)((h + 1) * 56 + w) * 768 + c]);
            if (v0 < m1e) { m2e = m1e; m1e = v0; } else if (v0 < m2e) m2e = v0;
            if (v1 < m1o) { m2o = m1o; m1o = v1; } else if (v1 < m2o) m2o = v1;
        }
        float* cm1 = mins;
        float* cm2 = mins + MINSEG;
        cm1[((b * 2 + 0) * 56 + w) * 384 + c] = m1e;
        cm1[((b * 2 + 1) * 56 + w) * 384 + c] = m1o;
        cm2[((b * 2 + 0) * 56 + w) * 384 + c] = m2e;
        cm2[((b * 2 + 1) * 56 + w) * 384 + c] = m2o;
    } else {
        int h = q - 56;
        for (int w = 0; w < 56; w += 2) {
            float v0 = bf2f(yb[(size_t)(h * 56 + w) * 768 + c]);
            float v1 = bf2f(yb[(size_t)(h * 56 + w + 1) * 768 + c]);
            if (v0 < m1e) { m2e = m1e; m1e = v0; } else if (v0 < m2e) m2e = v0;
            if (v1 < m1o) { m2o = m1o; m1o = v1; } else if (v1 < m2o) m2o = v1;
        }
        float* rm1 = mins + 2 * MINSEG;
        float* rm2 = mins + 3 * MINSEG;
        rm1[((b * 2 + 0) * 56 + h) * 384 + c] = m1e;
        rm1[((b * 2 + 1) * 56 + h) * 384 + c] = m1o;
        rm2[((b * 2 + 0) * 56 + h) * 384 + c] = m2e;
        rm2[((b * 2 + 1) * 56 + h) * 384 + c] = m2o;
    }
}

// ---------------- mrconv pass 2: combine -> y[:, 384:768] ----------------
__global__ __launch_bounds__(384)
void mr_comb(unsigned short* __restrict__ y, const float* __restrict__ mins)
{
    const int c = threadIdx.x;
    const int h = blockIdx.x;
    const int b = blockIdx.y;
    unsigned short* yb = y + (size_t)b * P_ * 768;
    const float* cm1 = mins;
    const float* cm2 = mins + MINSEG;
    const float* rm1 = mins + 2 * MINSEG;
    const float* rm2 = mins + 3 * MINSEG;
    const int parh = h & 1;
    float r1e = rm1[((b * 2 + 0) * 56 + h) * 384 + c];
    float r2e = rm2[((b * 2 + 0) * 56 + h) * 384 + c];
    float r1o = rm1[((b * 2 + 1) * 56 + h) * 384 + c];
    float r2o = rm2[((b * 2 + 1) * 56 + h) * 384 + c];
    #pragma unroll 2
    for (int w = 0; w < 56; ++w) {
        float v  = bf2f(yb[(size_t)(h * 56 + w) * 768 + c]);
        float c1 = cm1[((b * 2 + parh) * 56 + w) * 384 + c];
        float c2 = cm2[((b * 2 + parh) * 56 + w) * 384 + c];
        float mh = v > c1 ? c1 : c2;
        float rw1 = (w & 1) ? r1o : r1e;
        float rw2 = (w & 1) ? r2o : r2e;
        float mw = v > rw1 ? rw1 : rw2;
        float xj = fmaxf(0.0f, v - fminf(mh, mw));
        yb[(size_t)(h * 56 + w) * 768 + 384 + c] = f2bf(xj);
    }
}

extern "C" void kernel_launch(void* const* d_in, const int* in_sizes, int n_in,
                              void* d_out, int out_size, void* d_ws, size_t ws_size,
                              hipStream_t stream)
{
    const float* x      = (const float*)d_in[0];
    const float* fc1_w  = (const float*)d_in[1];
    const float* fc1_b  = (const float*)d_in[2];
    const float* fc1_g  = (const float*)d_in[3];
    const float* fc1_be = (const float*)d_in[4];
    const float* fc1_m  = (const float*)d_in[5];
    const float* fc1_v  = (const float*)d_in[6];
    const float* gc_w   = (const float*)d_in[7];
    const float* gc_b   = (const float*)d_in[8];
    const float* gc_g   = (const float*)d_in[9];
    const float* gc_be  = (const float*)d_in[10];
    const float* gc_m   = (const float*)d_in[11];
    const float* gc_v   = (const float*)d_in[12];
    const float* fc2_w  = (const float*)d_in[13];
    const float* fc2_b  = (const float*)d_in[14];
    const float* fc2_g  = (const float*)d_in[15];
    const float* fc2_be = (const float*)d_in[16];
    const float* fc2_m  = (const float*)d_in[17];
    const float* fc2_v  = (const float*)d_in[18];

    char* ws = (char*)d_ws;
    unsigned short* y   = (unsigned short*)ws;                       // [NTOT][768] bf16
    unsigned short* g   = y + (size_t)NTOT * 768;                    // [NTOT][768] bf16
    unsigned short* xT  = g + (size_t)NTOT * 768;                    // [NTOT][384] bf16
    unsigned short* wb1 = xT + (size_t)NTOT * 384;                   // [384][384]
    unsigned short* wb2 = wb1 + 384 * 384;                           // [768][768]
    unsigned short* wb3 = wb2 + 768 * 768;                           // [384][768]
    float* bn1 = (float*)(wb3 + 384 * 768);                          // [2][384]
    float* bn2 = bn1 + 2 * 384;                                      // [2][768]
    float* bn3 = bn2 + 2 * 768;                                      // [2][384]
    float* mins = bn3 + 2 * 384;                                     // 4 * MINSEG

    // weights->bf16 (1008 blocks) + BN fold (6 blocks)
    prep_wb<<<1014, 256, 0, stream>>>(fc1_w, gc_w, fc2_w, wb1, wb2, wb3,
                                      fc1_b, fc1_g, fc1_be, fc1_m, fc1_v,
                                      gc_b, gc_g, gc_be, gc_m, gc_v,
                                      fc2_b, fc2_g, fc2_be, fc2_m, fc2_v,
                                      bn1, bn2, bn3);
    prep_xT<<<dim3(6, 49, 16), 256, 0, stream>>>(x, xT);

    // y[:, 0:384] = bn(fc1 @ x)
    gemm1<<<dim3(3 * 392), 256, 0, stream>>>(wb1, xT, y, bn1);
    // y[:, 384:768] = mrconv (two-pass, coalesced)
    mr_min<<<dim3(112, 16), 384, 0, stream>>>(y, mins);
    mr_comb<<<dim3(56, 16), 384, 0, stream>>>(y, mins);
    // g = gelu(bn(gc @ y))
    gemm2<<<dim3(6 * 392), 256, 0, stream>>>(wb2, y, g, bn2);
    // out = bn(fc2 @ g) + x
    gemm3<<<dim3(3 * 392), 256, 0, stream>>>(wb3, g, (void*)d_out, bn3, x);
}